// Round 1
// baseline (381.444 us; speedup 1.0000x reference)
//
#include <hip/hip_runtime.h>

#define EDGES 400000
#define DIM 128

typedef __attribute__((ext_vector_type(8))) short bf16x8;
typedef __attribute__((ext_vector_type(4))) float f32x4;

// fp32 -> bf16 round-to-nearest-even (no NaN handling needed here)
__device__ __forceinline__ short f2bf(float f) {
    unsigned u = __builtin_bit_cast(unsigned, f);
    unsigned r = (u + 0x7fffu + ((u >> 16) & 1u)) >> 16;
    return (short)r;
}

// Rearrange W1 [768][384] fp32 -> bf16 frag-major for 16x16x32 MFMA B-operand:
// frag (nt, s): lane holds B[k = (lane>>4)*8 + j][n = lane&15], k-step s, n-tile nt.
// W1f[((nt*12+s)*64+lane)*8 + j] = bf16( W1[(nt*16+(lane&15))*384 + s*32+(lane>>4)*8+j] )
__global__ void prep_w1(const float* __restrict__ W1, short* __restrict__ W1f) {
    int idx = blockIdx.x * 256 + threadIdx.x;       // 294912 = 48*12*64*8
    int j    = idx & 7;
    int lane = (idx >> 3) & 63;
    int fs   = idx >> 9;                            // nt*12 + s
    int s    = fs % 12;
    int nt   = fs / 12;
    int n = nt * 16 + (lane & 15);
    int k = s * 32 + (lane >> 4) * 8 + j;
    W1f[idx] = f2bf(W1[n * 384 + k]);
}

// Block: 256 threads = 4 waves, 128 edges (each wave owns 2 M-tiles of 16 edges).
// A (feat) lives in registers; B (W1) streamed frag-major via async global_load_lds
// into double-buffered LDS; h never materialized (relu + W2 reduce in epilogue).
__global__ __launch_bounds__(256, 2)
void edge_mlp(const float* __restrict__ x,
              const int*   __restrict__ ei,      // [2][EDGES]
              const float* __restrict__ b1,      // [768]
              const float* __restrict__ W2,      // [768]
              const float* __restrict__ b2p,     // [1]
              const short* __restrict__ W1f,     // frag-major bf16 W1
              float* __restrict__ out)           // [EDGES]
{
    __shared__ short sB[2][12 * 512];            // 2 x 12 frags x 1KB = 24 KB

    const int tid  = threadIdx.x;
    const int lane = tid & 63;
    const int wave = tid >> 6;
    const int m    = lane & 15;                  // A-row / B-col / D-col index
    const int quad = lane >> 4;
    const int eb   = blockIdx.x * 128;

    // ---- async stage N-chunk 0 (12 frags; each wave issues 3) ----
    #pragma unroll
    for (int jj = 0; jj < 3; ++jj) {
        int s = wave * 3 + jj;
        __builtin_amdgcn_global_load_lds(
            (const __attribute__((address_space(1))) void*)(W1f + (s << 9) + lane * 8),
            (__attribute__((address_space(3))) void*)(&sB[0][s << 9]),
            16, 0, 0);
    }

    // ---- build A fragments in registers: 2 M-tiles x 12 K-steps ----
    // A-frag layout (m89/m120-verified): lane holds A[m=lane&15][k=quad*8+j].
    // feat col kc = 32*s + 8*quad + j ; sections: s 0-3 mean, 4-7 prod, 8-11 sqdiff,
    // all three from the SAME x columns -> each x chunk loaded once.
    bf16x8 afrag[2][12];
    #pragma unroll
    for (int T = 0; T < 2; ++T) {
        int e = eb + wave * 32 + T * 16 + m;
        const float* r0 = x + (size_t)ei[e] * DIM;
        const float* r1 = x + (size_t)ei[EDGES + e] * DIM;
        #pragma unroll
        for (int i = 0; i < 4; ++i) {
            int c = i * 32 + quad * 8;
            float4 a0 = *(const float4*)(r0 + c);
            float4 a1 = *(const float4*)(r0 + c + 4);
            float4 c0 = *(const float4*)(r1 + c);
            float4 c1 = *(const float4*)(r1 + c + 4);
            float t0[8] = {a0.x,a0.y,a0.z,a0.w,a1.x,a1.y,a1.z,a1.w};
            float t1[8] = {c0.x,c0.y,c0.z,c0.w,c1.x,c1.y,c1.z,c1.w};
            bf16x8 fm, fp, fd;
            #pragma unroll
            for (int j = 0; j < 8; ++j) {
                float aa = t0[j], bb = t1[j];
                fm[j] = f2bf((aa + bb) * 0.5f);
                fp[j] = f2bf(aa * bb);
                float dd = aa - bb;
                fd[j] = f2bf(dd * dd);
            }
            afrag[T][i]     = fm;   // mean      -> k in [0,128)
            afrag[T][i + 4] = fp;   // product   -> k in [128,256)
            afrag[T][i + 8] = fd;   // sq. diff  -> k in [256,384)
        }
    }

    float yp0[4] = {0.f, 0.f, 0.f, 0.f};
    float yp1[4] = {0.f, 0.f, 0.f, 0.f};

    __syncthreads();   // waits own global_load_lds (vmcnt) then barrier -> chunk 0 ready

    for (int nt = 0; nt < 48; ++nt) {
        const int cur = nt & 1;

        // prefetch next chunk into the other buffer (drains at end-of-iter barrier)
        if (nt + 1 < 48) {
            const short* src = W1f + (size_t)(nt + 1) * 6144;
            #pragma unroll
            for (int jj = 0; jj < 3; ++jj) {
                int s = wave * 3 + jj;
                __builtin_amdgcn_global_load_lds(
                    (const __attribute__((address_space(1))) void*)(src + (s << 9) + lane * 8),
                    (__attribute__((address_space(3))) void*)(&sB[cur ^ 1][s << 9]),
                    16, 0, 0);
            }
        }

        f32x4 acc0 = {0.f, 0.f, 0.f, 0.f};
        f32x4 acc1 = {0.f, 0.f, 0.f, 0.f};
        const bf16x8* bp = (const bf16x8*)sB[cur];
        #pragma unroll
        for (int s = 0; s < 12; ++s) {
            bf16x8 bfrag = bp[(s << 6) + lane];   // conflict-free: addr = s*1024 + lane*16
            acc0 = __builtin_amdgcn_mfma_f32_16x16x32_bf16(afrag[0][s], bfrag, acc0, 0, 0, 0);
            acc1 = __builtin_amdgcn_mfma_f32_16x16x32_bf16(afrag[1][s], bfrag, acc1, 0, 0, 0);
        }

        // epilogue: D layout col=lane&15, row=quad*4+r (m89-verified)
        int ng = nt * 16 + m;
        float bias = b1[ng];
        float w2v  = W2[ng];
        #pragma unroll
        for (int r = 0; r < 4; ++r) {
            float h0 = acc0[r] + bias;
            float h1 = acc1[r] + bias;
            yp0[r] = fmaf(fmaxf(h0, 0.f), w2v, yp0[r]);
            yp1[r] = fmaf(fmaxf(h1, 0.f), w2v, yp1[r]);
        }

        __syncthreads();   // prefetch drained + all waves done reading sB[cur]
    }

    // reduce the 16 columns held across lanes of each quad-group
    #pragma unroll
    for (int off = 8; off >= 1; off >>= 1) {
        #pragma unroll
        for (int r = 0; r < 4; ++r) {
            yp0[r] += __shfl_xor(yp0[r], off, 64);
            yp1[r] += __shfl_xor(yp1[r], off, 64);
        }
    }
    if (m == 0) {
        float b2v = b2p[0];
        int e0 = eb + wave * 32 + quad * 4;
        #pragma unroll
        for (int r = 0; r < 4; ++r) {
            out[e0 + r]      = yp0[r] + b2v;
            out[e0 + 16 + r] = yp1[r] + b2v;
        }
    }
}

extern "C" void kernel_launch(void* const* d_in, const int* in_sizes, int n_in,
                              void* d_out, int out_size, void* d_ws, size_t ws_size,
                              hipStream_t stream) {
    const float* x  = (const float*)d_in[0];
    const int*   ei = (const int*)  d_in[1];
    // d_in[2]=edge_attr3, d_in[3]=edge_attr4, d_in[4]=batch : unused by reference
    const float* W1 = (const float*)d_in[5];
    const float* b1 = (const float*)d_in[6];
    const float* W2 = (const float*)d_in[7];
    const float* b2 = (const float*)d_in[8];
    short* W1f = (short*)d_ws;                 // 589824 B frag-major bf16 W1
    float* out = (float*)d_out;

    prep_w1<<<1152, 256, 0, stream>>>(W1, W1f);            // 294912 elems
    edge_mlp<<<3125, 256, 0, stream>>>(x, ei, b1, W2, b2, W1f, out);
}